// Round 7
// baseline (560.752 us; speedup 1.0000x reference)
//
#include <hip/hip_runtime.h>

// WordAttention: mix = softmax(relu(c@W^T+b) @ relu(q@W^T+b)^T) @ q
// B=32, CL=2048, QL=512, DIM=512, fp32 in/out, fp16 MFMA compute (fp32 accum).
// R5 (5th submit; R3-R6 benches were broker/container failures, no signal):
// k_fused restructured to 4 waves x 128-wide slices, waves_per_eu(2)
// (256-reg budget: 128 AGPR acc + ~110 VGPR) with explicit register
// double-buffering of B-fragments -- R4's waves_per_eu(4) left only 64 VGPRs,
// forcing serialized B loads (exposed ~300cy L2 latency per 4-MFMA group,
// MfmaUtil 17%). Epilogue now bounces acc through LDS to emit full 2KB-row
// stores (R4 wrote 64B fragments -> 2x write amplification, 277MB vs 134MB).
// Fragment shuffle folded into producers (k_proj/k_prep_qt write qfS/qTS
// directly) -- kills both k_shuf_f16 launches.

#define BATCH 32
#define CL    2048
#define QL    512
#define DIM   512
#define CT    64      // c-rows per fused workgroup

typedef _Float16 f16x8 __attribute__((ext_vector_type(8)));
typedef _Float16 f16x4 __attribute__((ext_vector_type(4)));
typedef float    f32x4 __attribute__((ext_vector_type(4)));

#define LDP 72    // proj A-stage row (halfs): bank offset 36 dwords -> 2-way, free

// fragment-major layout: element (M=m, E=e) of a [M][512] f16 matrix lives at
// ((m>>4)*16 + (e>>5))*64*8 + (((e>>3)&3)*16 + (m&15))*8 + (e&7)
__device__ __forceinline__ size_t frag_off(int m, int e) {
    return (((size_t)(m >> 4) * 16 + (e >> 5)) * 64 + ((e >> 3) & 3) * 16 + (m & 15)) * 8 + (e & 7);
}

// ---- W: row-major fp32 [512][512] -> fragment-major fp16 ----
__global__ void k_shuf_f32(const float* __restrict__ in, _Float16* __restrict__ out) {
    size_t g = (size_t)blockIdx.x * 256 + threadIdx.x;
    int rt = (int)(g >> 10), ks = (int)(g >> 6) & 15, l = (int)g & 63;
    const float* src = in + ((size_t)(rt * 16 + (l & 15))) * 512 + ks * 32 + (l >> 4) * 8;
    float4 v0 = *(const float4*)src;
    float4 v1 = *(const float4*)(src + 4);
    f16x8 h = {(_Float16)v0.x, (_Float16)v0.y, (_Float16)v0.z, (_Float16)v0.w,
               (_Float16)v1.x, (_Float16)v1.y, (_Float16)v1.z, (_Float16)v1.w};
    *(f16x8*)(out + g * 8) = h;
}

// ---- prep: qTS[frag(b*512+d, j)] = fp16(q[b][j][d]) directly ----
__global__ void k_prep_qt(const float* __restrict__ q, _Float16* __restrict__ qTS) {
    __shared__ _Float16 t[64][65];
    int b  = blockIdx.x;
    int jt = blockIdx.y;            // QL/64
    int dt = blockIdx.z;            // DIM/64
    const float* src = q + ((size_t)b * QL + jt * 64) * DIM + dt * 64;
    int r0 = threadIdx.x >> 6;
    int cc = threadIdx.x & 63;
#pragma unroll
    for (int p = 0; p < 16; ++p) {
        int r = r0 + p * 4;
        t[r][cc] = (_Float16)src[(size_t)r * DIM + cc];
    }
    __syncthreads();
#pragma unroll
    for (int p = 0; p < 16; ++p) {
        int r = r0 + p * 4;         // local d
        int d = dt * 64 + r;
        int j = jt * 64 + cc;
        qTS[frag_off(b * 512 + d, j)] = t[cc][r];
    }
}

// ---- qf: relu(q @ W^T + b) -> qfS fragment-major directly ----
__global__ __launch_bounds__(256)
__attribute__((amdgpu_waves_per_eu(3)))
void k_projS(const float* __restrict__ X, const _Float16* __restrict__ WhS,
             const float* __restrict__ bias, _Float16* __restrict__ Y) {
    __shared__ __align__(16) _Float16 Ah[128 * LDP];
    int m0 = blockIdx.x * 128;
    int n0 = blockIdx.y * 128;
    int tid = threadIdx.x;
    int w = tid >> 6, lane = tid & 63;
    int col = lane & 15, quad = lane >> 4;
    int wm = (w >> 1) * 64, wn = (w & 1) * 64;
    int et0 = (n0 + wn) >> 4;

    f32x4 acc[4][4];
#pragma unroll
    for (int it = 0; it < 4; ++it)
#pragma unroll
        for (int jt = 0; jt < 4; ++jt) acc[it][jt] = (f32x4){0.f, 0.f, 0.f, 0.f};

    for (int kc = 0; kc < 8; ++kc) {       // BK=64
#pragma unroll
        for (int p = 0; p < 8; ++p) {
            int s = tid + p * 256;
            int r = s >> 4, c4 = (s & 15) * 4;
            float4 v = *(const float4*)(X + (size_t)(m0 + r) * DIM + kc * 64 + c4);
            f16x4 h = {(_Float16)v.x, (_Float16)v.y, (_Float16)v.z, (_Float16)v.w};
            *(f16x4*)&Ah[r * LDP + c4] = h;
        }
        __syncthreads();
#pragma unroll
        for (int kc2 = 0; kc2 < 2; ++kc2) {
            int ks = kc * 2 + kc2;
            f16x8 af[4], bf[4];
#pragma unroll
            for (int it = 0; it < 4; ++it)
                af[it] = *(const f16x8*)&Ah[(wm + it * 16 + col) * LDP + kc2 * 32 + quad * 8];
#pragma unroll
            for (int jt = 0; jt < 4; ++jt)
                bf[jt] = *(const f16x8*)(WhS + (((size_t)(et0 + jt) * 16 + ks) * 64 + lane) * 8);
#pragma unroll
            for (int it = 0; it < 4; ++it)
#pragma unroll
                for (int jt = 0; jt < 4; ++jt)
                    acc[it][jt] = __builtin_amdgcn_mfma_f32_16x16x32_f16(af[it], bf[jt], acc[it][jt], 0, 0, 0);
        }
        __syncthreads();
    }
#pragma unroll
    for (int jt = 0; jt < 4; ++jt) {
        int e = n0 + wn + jt * 16 + col;
        float bv = bias[e];
#pragma unroll
        for (int it = 0; it < 4; ++it)
#pragma unroll
            for (int r = 0; r < 4; ++r) {
                int m = m0 + wm + it * 16 + quad * 4 + r;
                Y[frag_off(m, e)] = (_Float16)fmaxf(acc[it][jt][r] + bv, 0.f);
            }
    }
}

// ================= fused kernel: 4 waves, 128-wide slices =================
#define AFREAD(AF, KC)                                                        \
    { int ku_ = (KC) * 4 + quad;                                              \
      _Pragma("unroll")                                                       \
      for (int it = 0; it < 4; ++it)                                          \
          AF[it] = *(const f16x8*)&At[(it * 16 + col) * DIM + ((ku_ ^ cs) << 3)]; }

#define MFMAS(AF, BF)                                                         \
    _Pragma("unroll")                                                         \
    for (int it = 0; it < 4; ++it)                                            \
        _Pragma("unroll")                                                     \
        for (int jt = 0; jt < 8; ++jt)                                        \
            acc[it][jt] = __builtin_amdgcn_mfma_f32_16x16x32_f16(AF[it], BF[jt], acc[it][jt], 0, 0, 0);

#define LOADB(DST, BASE, RT0, KC)                                             \
    _Pragma("unroll")                                                         \
    for (int jt = 0; jt < 8; ++jt)                                            \
        DST[jt] = *(const f16x8*)((BASE) + (((size_t)(((RT0) + jt) * 16 + (KC))) * 64 + lane) * 8);

// register-double-buffered K loop: B(kc+1) loads in flight under 32 MFMAs(kc)
#define PHASE(BASE, RT0)                                                      \
    { f16x8 ba_[8], bb_[8], af_[4];                                           \
      LOADB(ba_, BASE, RT0, 0)                                                \
      _Pragma("unroll")                                                       \
      for (int kk = 0; kk < 8; ++kk) {                                        \
          AFREAD(af_, kk * 2)                                                 \
          LOADB(bb_, BASE, RT0, kk * 2 + 1)                                   \
          MFMAS(af_, ba_)                                                     \
          AFREAD(af_, kk * 2 + 1)                                             \
          if (kk < 7) { LOADB(ba_, BASE, RT0, kk * 2 + 2) }                   \
          MFMAS(af_, bb_)                                                     \
      } }

#define ZEROACC                                                               \
    _Pragma("unroll")                                                         \
    for (int it = 0; it < 4; ++it)                                            \
        _Pragma("unroll")                                                     \
        for (int jt = 0; jt < 8; ++jt) acc[it][jt] = (f32x4){0.f, 0.f, 0.f, 0.f};

__global__ __launch_bounds__(256)
__attribute__((amdgpu_waves_per_eu(2)))
void k_fused(const float* __restrict__ C, const _Float16* __restrict__ WhS,
             const float* __restrict__ bias,
             const _Float16* __restrict__ qfS, const _Float16* __restrict__ qTS,
             float* __restrict__ out) {
    __shared__ __align__(16) _Float16 At[CT * DIM];   // 64 KB (c/cf, then P, then f32 bounce)
    __shared__ float redmax[4][CT];
    __shared__ float redsum[4][CT];
    float* fAt = (float*)At;

    // batch-affinity XCD swizzle: XCD x (= blockIdx%8 under round-robin
    // dispatch) runs only batches b ≡ x (mod 8); <=2 batches concurrent/XCD.
    int bx   = blockIdx.x;
    int xcd  = bx & 7;
    int slot = bx >> 3;                 // 0..127 per XCD
    int b    = xcd + 8 * (slot >> 5);   // 4 batches per XCD
    int c0   = (slot & 31) * CT;

    int tid   = threadIdx.x;
    int w     = tid >> 6, lane = tid & 63;
    int col   = lane & 15, quad = lane >> 4;
    int obase = w * 128;                // this wave's j/e/d column slice
    int cs    = col & 7;                // XOR key for swizzled A-frag reads
    int rt0q  = b * 32 + w * 8;         // fragment row-tile base into qfS/qTS

    // ---- stage c tile: 64 rows x 512 fp32 -> fp16, swizzled ----
    const float* cb = C + ((size_t)b * CL + c0) * DIM;
#pragma unroll
    for (int p = 0; p < 16; ++p) {
        int s = tid + p * 256;          // 0..4095
        int r = s >> 6, u = s & 63;     // row (= p*4+w, wave-uniform), 16B unit (= lane)
        const float* src = cb + (size_t)r * DIM + u * 8;
        float4 v0 = *(const float4*)src;
        float4 v1 = *(const float4*)(src + 4);
        f16x8 h = {(_Float16)v0.x, (_Float16)v0.y, (_Float16)v0.z, (_Float16)v0.w,
                   (_Float16)v1.x, (_Float16)v1.y, (_Float16)v1.z, (_Float16)v1.w};
        *(f16x8*)&At[r * DIM + ((u ^ (r & 7)) << 3)] = h;
    }
    __syncthreads();

    f32x4 acc[4][8];

    // ---- phase 0: cf = relu(c @ W^T + bias) ----
    ZEROACC
    PHASE(WhS, w * 8)
    __syncthreads();        // all waves done reading the c tile
    // bias + relu -> cf overwrites At (swizzled)
#pragma unroll
    for (int jt = 0; jt < 8; ++jt) {
        int e = obase + jt * 16 + col;
        float bv = bias[e];
        int ue = e >> 3, we = e & 7;
#pragma unroll
        for (int it = 0; it < 4; ++it)
#pragma unroll
            for (int r = 0; r < 4; ++r) {
                int m = it * 16 + quad * 4 + r;
                At[m * DIM + (((ue ^ (m & 7)) << 3) | we)] =
                    (_Float16)fmaxf(acc[it][jt][r] + bv, 0.f);
            }
    }
    __syncthreads();

    // ---- phase 2: S = cf @ qf^T ----
    ZEROACC
    PHASE(qfS, rt0q)

    // ---- phase 3: softmax over j ----
    float sm[4][4];
#pragma unroll
    for (int it = 0; it < 4; ++it)
#pragma unroll
        for (int r = 0; r < 4; ++r) {
            float m = -1e30f;
#pragma unroll
            for (int jt = 0; jt < 8; ++jt) m = fmaxf(m, acc[it][jt][r]);
            m = fmaxf(m, __shfl_xor(m, 1));
            m = fmaxf(m, __shfl_xor(m, 2));
            m = fmaxf(m, __shfl_xor(m, 4));
            m = fmaxf(m, __shfl_xor(m, 8));
            sm[it][r] = m;
        }
    if (col == 0) {
#pragma unroll
        for (int it = 0; it < 4; ++it)
#pragma unroll
            for (int r = 0; r < 4; ++r) redmax[w][it * 16 + quad * 4 + r] = sm[it][r];
    }
    __syncthreads();        // all phase-2 At reads done; P overwrite safe after this
#pragma unroll
    for (int it = 0; it < 4; ++it)
#pragma unroll
        for (int r = 0; r < 4; ++r) {
            int i = it * 16 + quad * 4 + r;
            float gm = fmaxf(fmaxf(redmax[0][i], redmax[1][i]),
                             fmaxf(redmax[2][i], redmax[3][i]));
            float s = 0.f;
#pragma unroll
            for (int jt = 0; jt < 8; ++jt) {
                float e = __expf(acc[it][jt][r] - gm);
                acc[it][jt][r] = e;
                s += e;
            }
            s += __shfl_xor(s, 1);
            s += __shfl_xor(s, 2);
            s += __shfl_xor(s, 4);
            s += __shfl_xor(s, 8);
            sm[it][r] = s;
        }
    if (col == 0) {
#pragma unroll
        for (int it = 0; it < 4; ++it)
#pragma unroll
            for (int r = 0; r < 4; ++r) redsum[w][it * 16 + quad * 4 + r] = sm[it][r];
    }
    __syncthreads();
#pragma unroll
    for (int it = 0; it < 4; ++it)
#pragma unroll
        for (int r = 0; r < 4; ++r) {
            int i = it * 16 + quad * 4 + r;
            float tot = redsum[0][i] + redsum[1][i] + redsum[2][i] + redsum[3][i];
            float inv = 1.f / tot;
#pragma unroll
            for (int jt = 0; jt < 8; ++jt) {
                int j = obase + jt * 16 + col;
                int uj = j >> 3, wj = j & 7;
                At[i * DIM + (((uj ^ (i & 7)) << 3) | wj)] =
                    (_Float16)(acc[it][jt][r] * inv);
            }
        }
    __syncthreads();        // P tile visible to all waves

    // ---- phase 4: out = P @ q ----
    ZEROACC
    PHASE(qTS, rt0q)
    __syncthreads();        // all P reads done; At reusable as f32 bounce

    // ---- epilogue: bounce acc through LDS (f32, 32 rows/half) for
    // full-line global stores. dword-swizzle key = quad<<4 (row>>2 & 3). ----
#pragma unroll
    for (int h = 0; h < 2; ++h) {
#pragma unroll
        for (int it = 2 * h; it < 2 * h + 2; ++it)
#pragma unroll
            for (int jt = 0; jt < 8; ++jt) {
                int d = obase + jt * 16 + col;
#pragma unroll
                for (int r = 0; r < 4; ++r) {
                    int lr = (it & 1) * 16 + quad * 4 + r;     // 0..31
                    int key = ((lr >> 2) & 3) << 4;
                    fAt[lr * DIM + (d ^ key)] = acc[it][jt][r];
                }
            }
        __syncthreads();
        const float* outrow0 = out + ((size_t)b * CL + c0 + h * 32) * DIM;
#pragma unroll
        for (int p = 0; p < 8; ++p) {
            int o   = p * 2048 + tid * 8;     // f32 linear index in half-tile
            int row = o >> 9;                 // wave-uniform (= p*4 + w)
            int d0  = o & 511;                // = lane*8
            int key = ((row >> 2) & 3) << 4;
            int idx = row * DIM + (d0 ^ key);
            f32x4 v0 = *(const f32x4*)&fAt[idx];
            f32x4 v1 = *(const f32x4*)&fAt[idx + 4];
            float* dst = (float*)outrow0 + (size_t)row * DIM + d0;
            *(f32x4*)dst = v0;
            *(f32x4*)(dst + 4) = v1;
        }
        if (h == 0) __syncthreads();
    }
}

extern "C" void kernel_launch(void* const* d_in, const int* in_sizes, int n_in,
                              void* d_out, int out_size, void* d_ws, size_t ws_size,
                              hipStream_t stream) {
    const float* c    = (const float*)d_in[0];
    const float* q    = (const float*)d_in[1];
    const float* W    = (const float*)d_in[2];
    const float* bias = (const float*)d_in[3];
    float* out = (float*)d_out;

    // ws: WhS 512K | qfS 16M | qTS 16M
    char* ws = (char*)d_ws;
    _Float16* WhS = (_Float16*)ws;
    _Float16* qfS = (_Float16*)(ws + (1u << 19));
    _Float16* qTS = (_Float16*)(ws + (1u << 19) + (1u << 24));

    k_shuf_f32<<<128, 256, 0, stream>>>(W, WhS);                           // W -> WhS
    k_projS<<<dim3(BATCH * QL / 128, 4), 256, 0, stream>>>(q, WhS, bias, qfS);
    k_prep_qt<<<dim3(BATCH, QL / 64, DIM / 64), 256, 0, stream>>>(q, qTS);
    k_fused<<<BATCH * (CL / CT), 256, 0, stream>>>(c, WhS, bias, qfS, qTS, out);
}

// Round 8
// 404.592 us; speedup vs baseline: 1.3860x; 1.3860x over previous
//
#include <hip/hip_runtime.h>

// WordAttention: mix = softmax(relu(c@W^T+b) @ relu(q@W^T+b)^T) @ q
// B=32, CL=2048, QL=512, DIM=512, fp32 in/out, fp16 MFMA compute (fp32 accum).
// R6: fragment layout v2 -- the 8 B-fragments a wave consumes at one kc are
// now CONTIGUOUS (layout [rb][kc][rj 0..7][lane][8]), so LOADB = 1 base addr
// + 8 loads with immediate offsets (jt*1024B < 8KB). R5 spilled: per-jt
// fragments were 16KB apart -> 8x2 addr VGPRs per buffer -> demand ~280 regs
// vs 256 budget -> B buffers spilled to scratch in the hot loop (measured:
// WRITE 431MB vs 134MB output, FETCH +90MB, MfmaUtil 11.7%, 353us).
// v2 cuts address pressure ~30 VGPRs; acc 128 AGPR + ~100 VGPR fits clean.

#define BATCH 32
#define CL    2048
#define QL    512
#define DIM   512
#define CT    64      // c-rows per fused workgroup

typedef _Float16 f16x8 __attribute__((ext_vector_type(8)));
typedef _Float16 f16x4 __attribute__((ext_vector_type(4)));
typedef float    f32x4 __attribute__((ext_vector_type(4)));

#define LDP 72    // proj A-stage row (halfs): bank offset 36 dwords -> 2-way, free

// fragment-major layout v2 for [M][512] f16: element (m, e) lives at
//   rt=m>>4, rb=rt>>3, rj=rt&7, kc=e>>5, lane=((e>>3)&3)*16+(m&15)
//   off = (((rb*16 + kc)*8 + rj)*64 + lane)*8 + (e&7)
// -> for fixed (rb,kc), the 8 rj-fragments are contiguous 1KB blocks.
__device__ __forceinline__ size_t frag_off(int m, int e) {
    int rt = m >> 4, rb = rt >> 3, rj = rt & 7;
    int kc = e >> 5, lane = ((e >> 3) & 3) * 16 + (m & 15);
    return ((((size_t)rb * 16 + kc) * 8 + rj) * 64 + lane) * 8 + (e & 7);
}

// ---- W: row-major fp32 [512][512] -> fragment-major v2 fp16 ----
__global__ void k_shuf_f32(const float* __restrict__ in, _Float16* __restrict__ out) {
    size_t g = (size_t)blockIdx.x * 256 + threadIdx.x;   // g = ((rb*16+kc)*8+rj)*64+lane
    int l  = (int)g & 63;
    int rj = (int)(g >> 6) & 7;
    int kc = (int)(g >> 9) & 15;
    int rb = (int)(g >> 13);
    int m  = (rb * 8 + rj) * 16 + (l & 15);
    const float* src = in + (size_t)m * 512 + kc * 32 + (l >> 4) * 8;
    float4 v0 = *(const float4*)src;
    float4 v1 = *(const float4*)(src + 4);
    f16x8 h = {(_Float16)v0.x, (_Float16)v0.y, (_Float16)v0.z, (_Float16)v0.w,
               (_Float16)v1.x, (_Float16)v1.y, (_Float16)v1.z, (_Float16)v1.w};
    *(f16x8*)(out + g * 8) = h;
}

// ---- prep: qTS[frag(b*512+d, j)] = fp16(q[b][j][d]) directly ----
__global__ void k_prep_qt(const float* __restrict__ q, _Float16* __restrict__ qTS) {
    __shared__ _Float16 t[64][65];
    int b  = blockIdx.x;
    int jt = blockIdx.y;            // QL/64
    int dt = blockIdx.z;            // DIM/64
    const float* src = q + ((size_t)b * QL + jt * 64) * DIM + dt * 64;
    int r0 = threadIdx.x >> 6;
    int cc = threadIdx.x & 63;
#pragma unroll
    for (int p = 0; p < 16; ++p) {
        int r = r0 + p * 4;
        t[r][cc] = (_Float16)src[(size_t)r * DIM + cc];
    }
    __syncthreads();
#pragma unroll
    for (int p = 0; p < 16; ++p) {
        int r = r0 + p * 4;         // local d
        int d = dt * 64 + r;
        int j = jt * 64 + cc;
        qTS[frag_off(b * 512 + d, j)] = t[cc][r];
    }
}

// ---- qf: relu(q @ W^T + b) -> qfS fragment-major v2 directly ----
__global__ __launch_bounds__(256)
__attribute__((amdgpu_waves_per_eu(3)))
void k_projS(const float* __restrict__ X, const _Float16* __restrict__ WhS,
             const float* __restrict__ bias, _Float16* __restrict__ Y) {
    __shared__ __align__(16) _Float16 Ah[128 * LDP];
    int m0 = blockIdx.x * 128;
    int n0 = blockIdx.y * 128;
    int tid = threadIdx.x;
    int w = tid >> 6, lane = tid & 63;
    int col = lane & 15, quad = lane >> 4;
    int wm = (w >> 1) * 64, wn = (w & 1) * 64;
    int et0 = (n0 + wn) >> 4;       // multiple of 4; et0&7 in {0,4}

    f32x4 acc[4][4];
#pragma unroll
    for (int it = 0; it < 4; ++it)
#pragma unroll
        for (int jt = 0; jt < 4; ++jt) acc[it][jt] = (f32x4){0.f, 0.f, 0.f, 0.f};

    for (int kc = 0; kc < 8; ++kc) {       // BK=64
#pragma unroll
        for (int p = 0; p < 8; ++p) {
            int s = tid + p * 256;
            int r = s >> 4, c4 = (s & 15) * 4;
            float4 v = *(const float4*)(X + (size_t)(m0 + r) * DIM + kc * 64 + c4);
            f16x4 h = {(_Float16)v.x, (_Float16)v.y, (_Float16)v.z, (_Float16)v.w};
            *(f16x4*)&Ah[r * LDP + c4] = h;
        }
        __syncthreads();
#pragma unroll
        for (int kc2 = 0; kc2 < 2; ++kc2) {
            int ks = kc * 2 + kc2;
            f16x8 af[4], bf[4];
#pragma unroll
            for (int it = 0; it < 4; ++it)
                af[it] = *(const f16x8*)&Ah[(wm + it * 16 + col) * LDP + kc2 * 32 + quad * 8];
            const _Float16* wb = WhS +
                ((((size_t)(et0 >> 3) * 16 + ks) * 8 + (et0 & 7)) * 64 + lane) * 8;
#pragma unroll
            for (int jt = 0; jt < 4; ++jt)
                bf[jt] = *(const f16x8*)(wb + jt * 512);
#pragma unroll
            for (int it = 0; it < 4; ++it)
#pragma unroll
                for (int jt = 0; jt < 4; ++jt)
                    acc[it][jt] = __builtin_amdgcn_mfma_f32_16x16x32_f16(af[it], bf[jt], acc[it][jt], 0, 0, 0);
        }
        __syncthreads();
    }
#pragma unroll
    for (int jt = 0; jt < 4; ++jt) {
        int e = n0 + wn + jt * 16 + col;
        float bv = bias[e];
#pragma unroll
        for (int it = 0; it < 4; ++it)
#pragma unroll
            for (int r = 0; r < 4; ++r) {
                int m = m0 + wm + it * 16 + quad * 4 + r;
                Y[frag_off(m, e)] = (_Float16)fmaxf(acc[it][jt][r] + bv, 0.f);
            }
    }
}

// ================= fused kernel: 4 waves, 128-wide slices =================
#define AFREAD(AF, KC)                                                        \
    { int ku_ = (KC) * 4 + quad;                                              \
      _Pragma("unroll")                                                       \
      for (int it = 0; it < 4; ++it)                                          \
          AF[it] = *(const f16x8*)&At[(it * 16 + col) * DIM + ((ku_ ^ cs) << 3)]; }

#define MFMAS(AF, BF)                                                         \
    _Pragma("unroll")                                                         \
    for (int it = 0; it < 4; ++it)                                            \
        _Pragma("unroll")                                                     \
        for (int jt = 0; jt < 8; ++jt)                                        \
            acc[it][jt] = __builtin_amdgcn_mfma_f32_16x16x32_f16(AF[it], BF[jt], acc[it][jt], 0, 0, 0);

// v2 layout: 8 fragments for (RB, kc) are contiguous 1KB blocks -> one base
// pointer, 8 loads with immediate offsets (jt*1024B, folds into offset:).
#define LOADB(DST, BASE, RB, KC)                                              \
    { const _Float16* p_ = (BASE) +                                           \
          ((((size_t)(RB) * 16 + (KC)) * 8) * 64 + lane) * 8;                 \
      _Pragma("unroll")                                                       \
      for (int jt = 0; jt < 8; ++jt)                                          \
          DST[jt] = *(const f16x8*)(p_ + jt * 512); }

// register-double-buffered K loop: B(kc+1) loads in flight under 32 MFMAs(kc)
#define PHASE(BASE, RB)                                                       \
    { f16x8 ba_[8], bb_[8], af_[4];                                           \
      LOADB(ba_, BASE, RB, 0)                                                 \
      _Pragma("unroll")                                                       \
      for (int kk = 0; kk < 8; ++kk) {                                        \
          AFREAD(af_, kk * 2)                                                 \
          LOADB(bb_, BASE, RB, kk * 2 + 1)                                    \
          MFMAS(af_, ba_)                                                     \
          AFREAD(af_, kk * 2 + 1)                                             \
          if (kk < 7) { LOADB(ba_, BASE, RB, kk * 2 + 2) }                    \
          MFMAS(af_, bb_)                                                     \
      } }

#define ZEROACC                                                               \
    _Pragma("unroll")                                                         \
    for (int it = 0; it < 4; ++it)                                            \
        _Pragma("unroll")                                                     \
        for (int jt = 0; jt < 8; ++jt) acc[it][jt] = (f32x4){0.f, 0.f, 0.f, 0.f};

__global__ __launch_bounds__(256)
__attribute__((amdgpu_waves_per_eu(2)))
void k_fused(const float* __restrict__ C, const _Float16* __restrict__ WhS,
             const float* __restrict__ bias,
             const _Float16* __restrict__ qfS, const _Float16* __restrict__ qTS,
             float* __restrict__ out) {
    __shared__ __align__(16) _Float16 At[CT * DIM];   // 64 KB (c/cf, then P, then f32 bounce)
    __shared__ float redmax[4][CT];
    __shared__ float redsum[4][CT];
    float* fAt = (float*)At;

    // batch-affinity XCD swizzle: XCD x (= blockIdx%8 under round-robin
    // dispatch) runs only batches b ≡ x (mod 8); <=2 batches concurrent/XCD.
    int bx   = blockIdx.x;
    int xcd  = bx & 7;
    int slot = bx >> 3;                 // 0..127 per XCD
    int b    = xcd + 8 * (slot >> 5);   // 4 batches per XCD
    int c0   = (slot & 31) * CT;

    int tid   = threadIdx.x;
    int w     = tid >> 6, lane = tid & 63;
    int col   = lane & 15, quad = lane >> 4;
    int obase = w * 128;                // this wave's j/e/d column slice
    int cs    = col & 7;                // XOR key for swizzled A-frag reads
    int rbq   = b * 4 + w;              // v2 row-block base into qfS/qTS

    // ---- stage c tile: 64 rows x 512 fp32 -> fp16, swizzled ----
    const float* cb = C + ((size_t)b * CL + c0) * DIM;
#pragma unroll
    for (int p = 0; p < 16; ++p) {
        int s = tid + p * 256;          // 0..4095
        int r = s >> 6, u = s & 63;     // row (= p*4+w, wave-uniform), 16B unit (= lane)
        const float* src = cb + (size_t)r * DIM + u * 8;
        float4 v0 = *(const float4*)src;
        float4 v1 = *(const float4*)(src + 4);
        f16x8 h = {(_Float16)v0.x, (_Float16)v0.y, (_Float16)v0.z, (_Float16)v0.w,
                   (_Float16)v1.x, (_Float16)v1.y, (_Float16)v1.z, (_Float16)v1.w};
        *(f16x8*)&At[r * DIM + ((u ^ (r & 7)) << 3)] = h;
    }
    __syncthreads();

    f32x4 acc[4][8];

    // ---- phase 0: cf = relu(c @ W^T + bias) ----
    ZEROACC
    PHASE(WhS, w)
    __syncthreads();        // all waves done reading the c tile
    // bias + relu -> cf overwrites At (swizzled)
#pragma unroll
    for (int jt = 0; jt < 8; ++jt) {
        int e = obase + jt * 16 + col;
        float bv = bias[e];
        int ue = e >> 3, we = e & 7;
#pragma unroll
        for (int it = 0; it < 4; ++it)
#pragma unroll
            for (int r = 0; r < 4; ++r) {
                int m = it * 16 + quad * 4 + r;
                At[m * DIM + (((ue ^ (m & 7)) << 3) | we)] =
                    (_Float16)fmaxf(acc[it][jt][r] + bv, 0.f);
            }
    }
    __syncthreads();

    // ---- phase 2: S = cf @ qf^T ----
    ZEROACC
    PHASE(qfS, rbq)

    // ---- phase 3: softmax over j ----
    float sm[4][4];
#pragma unroll
    for (int it = 0; it < 4; ++it)
#pragma unroll
        for (int r = 0; r < 4; ++r) {
            float m = -1e30f;
#pragma unroll
            for (int jt = 0; jt < 8; ++jt) m = fmaxf(m, acc[it][jt][r]);
            m = fmaxf(m, __shfl_xor(m, 1));
            m = fmaxf(m, __shfl_xor(m, 2));
            m = fmaxf(m, __shfl_xor(m, 4));
            m = fmaxf(m, __shfl_xor(m, 8));
            sm[it][r] = m;
        }
    if (col == 0) {
#pragma unroll
        for (int it = 0; it < 4; ++it)
#pragma unroll
            for (int r = 0; r < 4; ++r) redmax[w][it * 16 + quad * 4 + r] = sm[it][r];
    }
    __syncthreads();        // all phase-2 At reads done; P overwrite safe after this
#pragma unroll
    for (int it = 0; it < 4; ++it)
#pragma unroll
        for (int r = 0; r < 4; ++r) {
            int i = it * 16 + quad * 4 + r;
            float gm = fmaxf(fmaxf(redmax[0][i], redmax[1][i]),
                             fmaxf(redmax[2][i], redmax[3][i]));
            float s = 0.f;
#pragma unroll
            for (int jt = 0; jt < 8; ++jt) {
                float e = __expf(acc[it][jt][r] - gm);
                acc[it][jt][r] = e;
                s += e;
            }
            s += __shfl_xor(s, 1);
            s += __shfl_xor(s, 2);
            s += __shfl_xor(s, 4);
            s += __shfl_xor(s, 8);
            sm[it][r] = s;
        }
    if (col == 0) {
#pragma unroll
        for (int it = 0; it < 4; ++it)
#pragma unroll
            for (int r = 0; r < 4; ++r) redsum[w][it * 16 + quad * 4 + r] = sm[it][r];
    }
    __syncthreads();
#pragma unroll
    for (int it = 0; it < 4; ++it)
#pragma unroll
        for (int r = 0; r < 4; ++r) {
            int i = it * 16 + quad * 4 + r;
            float tot = redsum[0][i] + redsum[1][i] + redsum[2][i] + redsum[3][i];
            float inv = 1.f / tot;
#pragma unroll
            for (int jt = 0; jt < 8; ++jt) {
                int j = obase + jt * 16 + col;
                int uj = j >> 3, wj = j & 7;
                At[i * DIM + (((uj ^ (i & 7)) << 3) | wj)] =
                    (_Float16)(acc[it][jt][r] * inv);
            }
        }
    __syncthreads();        // P tile visible to all waves

    // ---- phase 4: out = P @ q ----
    ZEROACC
    PHASE(qTS, rbq)
    __syncthreads();        // all P reads done; At reusable as f32 bounce

    // ---- epilogue: bounce acc through LDS (f32, 32 rows/half) for
    // full-line global stores. dword-swizzle key = quad<<4 (row>>2 & 3). ----
#pragma unroll
    for (int h = 0; h < 2; ++h) {
#pragma unroll
        for (int it = 2 * h; it < 2 * h + 2; ++it)
#pragma unroll
            for (int jt = 0; jt < 8; ++jt) {
                int d = obase + jt * 16 + col;
#pragma unroll
                for (int r = 0; r < 4; ++r) {
                    int lr = (it & 1) * 16 + quad * 4 + r;     // 0..31
                    int key = ((lr >> 2) & 3) << 4;
                    fAt[lr * DIM + (d ^ key)] = acc[it][jt][r];
                }
            }
        __syncthreads();
        const float* outrow0 = out + ((size_t)b * CL + c0 + h * 32) * DIM;
#pragma unroll
        for (int p = 0; p < 8; ++p) {
            int o   = p * 2048 + tid * 8;     // f32 linear index in half-tile
            int row = o >> 9;                 // wave-uniform (= p*4 + w)
            int d0  = o & 511;                // = lane*8
            int key = ((row >> 2) & 3) << 4;
            int idx = row * DIM + (d0 ^ key);
            f32x4 v0 = *(const f32x4*)&fAt[idx];
            f32x4 v1 = *(const f32x4*)&fAt[idx + 4];
            float* dst = (float*)outrow0 + (size_t)row * DIM + d0;
            *(f32x4*)dst = v0;
            *(f32x4*)(dst + 4) = v1;
        }
        if (h == 0) __syncthreads();
    }
}

extern "C" void kernel_launch(void* const* d_in, const int* in_sizes, int n_in,
                              void* d_out, int out_size, void* d_ws, size_t ws_size,
                              hipStream_t stream) {
    const float* c    = (const float*)d_in[0];
    const float* q    = (const float*)d_in[1];
    const float* W    = (const float*)d_in[2];
    const float* bias = (const float*)d_in[3];
    float* out = (float*)d_out;

    // ws: WhS 512K | qfS 16M | qTS 16M
    char* ws = (char*)d_ws;
    _Float16* WhS = (_Float16*)ws;
    _Float16* qfS = (_Float16*)(ws + (1u << 19));
    _Float16* qTS = (_Float16*)(ws + (1u << 19) + (1u << 24));

    k_shuf_f32<<<128, 256, 0, stream>>>(W, WhS);                           // W -> WhS
    k_projS<<<dim3(BATCH * QL / 128, 4), 256, 0, stream>>>(q, WhS, bias, qfS);
    k_prep_qt<<<dim3(BATCH, QL / 64, DIM / 64), 256, 0, stream>>>(q, qTS);
    k_fused<<<BATCH * (CL / CT), 256, 0, stream>>>(c, WhS, bias, qfS, qTS, out);
}